// Round 1
// baseline (897.750 us; speedup 1.0000x reference)
//
#include <hip/hip_runtime.h>
#include <math.h>
#include <stddef.h>

#define BB 32
#define LL 2048
#define DD 1024
#define HH 256
#define NSTEPS 4
#define RD 8192
#define G3 768

#define OUT_REGS 67108864UL
#define OUT_PO   67371008UL
#define OUT_TR   67403776UL

__device__ __forceinline__ float sigf(float x){ return 1.0f/(1.0f+expf(-x)); }
__device__ __forceinline__ float geluf(float x){ return x*0.5f*(1.0f+erff(x*0.70710678118654752f)); }

// ---------------- pooled = mean_L x ----------------
__global__ __launch_bounds__(256) void k_pool_part(const float* __restrict__ x, float* __restrict__ part){
  const int blk = blockIdx.x;          // b*32 + c
  const int b = blk >> 5, c = blk & 31;
  const int t = threadIdx.x;
  const float* xp = x + (size_t)b*LL*DD + (size_t)c*64*DD + t*4;
  float ax=0.f, ay=0.f, az=0.f, aw=0.f;
  for (int l=0;l<64;++l){
    float4 v = *(const float4*)(xp + (size_t)l*DD);
    ax+=v.x; ay+=v.y; az+=v.z; aw+=v.w;
  }
  float4 o; o.x=ax; o.y=ay; o.z=az; o.w=aw;
  *(float4*)(part + (size_t)blk*DD + t*4) = o;
}

__global__ __launch_bounds__(256) void k_pool_fin(const float* __restrict__ part, float* __restrict__ pooled,
                                                  const float* __restrict__ h0, float* __restrict__ h,
                                                  float* __restrict__ halt){
  const int b = blockIdx.x, t = threadIdx.x;
  float ax=0.f, ay=0.f, az=0.f, aw=0.f;
  for (int c=0;c<32;++c){
    float4 v = *(const float4*)(part + (size_t)(b*32+c)*DD + t*4);
    ax+=v.x; ay+=v.y; az+=v.z; aw+=v.w;
  }
  const float inv = 1.0f/(float)LL;
  float4 o; o.x=ax*inv; o.y=ay*inv; o.z=az*inv; o.w=aw*inv;
  *(float4*)(pooled + (size_t)b*DD + t*4) = o;
  h[b*HH + t] = h0[t];
  if (t==0) halt[b] = 0.f;
}

// ---------------- e1 = gelu(pooled @ W_e1 + b_e1) ----------------
__global__ __launch_bounds__(256) void k_e1(const float* __restrict__ pooled, const float* __restrict__ We1,
                                            const float* __restrict__ be1, float* __restrict__ e1){
  __shared__ float p[DD];
  const int b = blockIdx.x, t = threadIdx.x;
  for (int i=t;i<DD;i+=256) p[i] = pooled[b*DD+i];
  __syncthreads();
  float a0=0.f,a1=0.f,a2=0.f,a3=0.f;
  for (int k=0;k<DD;k+=4){
    a0 += p[k]  *We1[(k)*HH + t];
    a1 += p[k+1]*We1[(k+1)*HH + t];
    a2 += p[k+2]*We1[(k+2)*HH + t];
    a3 += p[k+3]*We1[(k+3)*HH + t];
  }
  float a = (a0+a1)+(a2+a3) + be1[t];
  e1[b*HH + t] = geluf(a);
}

// ---------------- generic B-shared partial matmul ----------------
// out_part[(kc*32 + b)*ldw + n] = sum_{k in [kc*128, kc*128+128)} in[b*in_ld + k] * W[(row_off+k)*ldw + n]
// grid: (N/64, K/128), block 128 threads. LDS: A transposed-padded + W tile.
#define MM_KC 128
#define ATS 516  // per-bq stride: 128*4 + 4

__device__ __forceinline__ void mm_compute_store(const float* At, const float* Wt,
                                                 float* __restrict__ part, int kc, int n0, int ldw, int t){
  const int nq = t & 15, bq = t >> 4;
  float acc00=0,acc01=0,acc02=0,acc03=0, acc10=0,acc11=0,acc12=0,acc13=0;
  float acc20=0,acc21=0,acc22=0,acc23=0, acc30=0,acc31=0,acc32=0,acc33=0;
  const float4* A4 = (const float4*)At + bq*129;   // 516/4
  const float4* W4 = (const float4*)Wt + nq;
  #pragma unroll 4
  for (int kk=0; kk<MM_KC; ++kk){
    float4 a = A4[kk];
    float4 w = W4[kk*16];
    acc00 += a.x*w.x; acc01 += a.x*w.y; acc02 += a.x*w.z; acc03 += a.x*w.w;
    acc10 += a.y*w.x; acc11 += a.y*w.y; acc12 += a.y*w.z; acc13 += a.y*w.w;
    acc20 += a.z*w.x; acc21 += a.z*w.y; acc22 += a.z*w.z; acc23 += a.z*w.w;
    acc30 += a.w*w.x; acc31 += a.w*w.y; acc32 += a.w*w.z; acc33 += a.w*w.w;
  }
  float* pp = part + (size_t)(kc*32 + bq*4)*ldw + n0 + nq*4;
  float4 o;
  o.x=acc00;o.y=acc01;o.z=acc02;o.w=acc03; *(float4*)(pp + 0*(size_t)ldw) = o;
  o.x=acc10;o.y=acc11;o.z=acc12;o.w=acc13; *(float4*)(pp + 1*(size_t)ldw) = o;
  o.x=acc20;o.y=acc21;o.z=acc22;o.w=acc23; *(float4*)(pp + 2*(size_t)ldw) = o;
  o.x=acc30;o.y=acc31;o.z=acc32;o.w=acc33; *(float4*)(pp + 3*(size_t)ldw) = o;
}

__global__ __launch_bounds__(128) void k_mm_part(const float* __restrict__ in, int in_ld,
                                                 const float* __restrict__ W, int row_off, int ldw,
                                                 float* __restrict__ part){
  __shared__ float At[8*ATS];
  __shared__ float Wt[MM_KC*64];
  const int t = threadIdx.x;
  const int nb = blockIdx.x, kc = blockIdx.y;
  const int k0 = kc*MM_KC, n0 = nb*64;
  #pragma unroll
  for (int rep=0; rep<8; ++rep){
    int idx = t + rep*128;
    int b = idx & 31, k4 = idx >> 5;
    float4 g = *(const float4*)(in + (size_t)b*in_ld + k0 + k4*4);
    float* a = At + (b>>2)*ATS + k4*16 + (b&3);
    a[0]=g.x; a[4]=g.y; a[8]=g.z; a[12]=g.w;
  }
  #pragma unroll
  for (int rep=0; rep<16; ++rep){
    int idx = t + rep*128;
    int k = idx >> 4, nq4 = idx & 15;
    *(float4*)(Wt + k*64 + nq4*4) = *(const float4*)(W + (size_t)(row_off + k0 + k)*ldw + n0 + nq4*4);
  }
  __syncthreads();
  mm_compute_store(At, Wt, part, kc, n0, ldw, t);
}

// attn second matmul: A assembled as v' = sum_l p8b[l] + opw6*bv, then @ Wo
__global__ __launch_bounds__(128) void k_mm_attn(const float* __restrict__ p8b, const float* __restrict__ opw,
                                                 const float* __restrict__ bv, const float* __restrict__ Wo,
                                                 float* __restrict__ p10){
  __shared__ float At[8*ATS];
  __shared__ float Wt[MM_KC*64];
  const int t = threadIdx.x;
  const int nb = blockIdx.x, kc = blockIdx.y;
  const int k0 = kc*MM_KC, n0 = nb*64;
  #pragma unroll
  for (int rep=0; rep<8; ++rep){
    int idx = t + rep*128;
    int b = idx & 31, k4 = idx >> 5;
    float w6 = opw[b*16 + 6];
    const float* bvp = bv + k0 + k4*4;
    float gx = w6*bvp[0], gy = w6*bvp[1], gz = w6*bvp[2], gw = w6*bvp[3];
    for (int l=0;l<8;++l){
      const float4 pv = *(const float4*)(p8b + (size_t)(l*32+b)*DD + k0 + k4*4);
      gx += pv.x; gy += pv.y; gz += pv.z; gw += pv.w;
    }
    float* a = At + (b>>2)*ATS + k4*16 + (b&3);
    a[0]=gx; a[4]=gy; a[8]=gz; a[12]=gw;
  }
  #pragma unroll
  for (int rep=0; rep<16; ++rep){
    int idx = t + rep*128;
    int k = idx >> 4, nq4 = idx & 15;
    *(float4*)(Wt + k*64 + nq4*4) = *(const float4*)(Wo + (size_t)(k0 + k)*DD + n0 + nq4*4);
  }
  __syncthreads();
  mm_compute_store(At, Wt, p10, kc, n0, DD, t);
}

// regs = e2part(2 layers) + b_e2
__global__ __launch_bounds__(256) void k_e2fin(const float* __restrict__ part, const float* __restrict__ be2,
                                               float* __restrict__ regs){
  int gid = blockIdx.x*256 + threadIdx.x;   // 32*8192 elements / grid 1024
  int b = gid >> 13, n = gid & 8191;
  regs[gid] = be2[n] + part[(size_t)(0*32+b)*RD + n] + part[(size_t)(1*32+b)*RD + n];
}

// ---------------- per-step control ----------------
__global__ __launch_bounds__(256) void k_control(int s,
    const float* __restrict__ u,
    const float* __restrict__ gip_part, const float* __restrict__ gi_part,
    const float* __restrict__ b_ih,
    const float* __restrict__ W_hh, const float* __restrict__ b_hh,
    const float* __restrict__ W_op, const float* __restrict__ b_op,
    const float* __restrict__ W_src, const float* __restrict__ b_src,
    const float* __restrict__ W_dst, const float* __restrict__ b_dst,
    const float* __restrict__ W_aux, const float* __restrict__ b_aux,
    const float* __restrict__ regs,
    float* __restrict__ h, float* __restrict__ halt,
    float* __restrict__ opw_ws, float* __restrict__ dstw_ws, float* __restrict__ live_ws,
    float* __restrict__ src_ws, float* __restrict__ dst_ws,
    float* __restrict__ tvec_ws, float* __restrict__ avec_ws,
    float* __restrict__ trace_out)
{
  const int b = blockIdx.x, t = threadIdx.x;
  __shared__ float gi[G3], gh[G3], hold[HH], hnew[HH], logit[40], wsm[40];
  hold[t] = h[b*HH + t];
  #pragma unroll
  for (int j=0;j<3;++j){
    int n = t + j*256;
    float a = b_ih[n];
    for (int l=0;l<8;++l)  a += gip_part[(size_t)(l*BB+b)*G3 + n];
    for (int l=0;l<64;++l) a += gi_part[(size_t)(l*BB+b)*G3 + n];
    gi[n] = a;
  }
  __syncthreads();
  #pragma unroll
  for (int j=0;j<3;++j){
    int n = t + j*256;
    float a = b_hh[n];
    #pragma unroll 4
    for (int k=0;k<HH;++k) a += hold[k]*W_hh[k*G3 + n];
    gh[n] = a;
  }
  __syncthreads();
  {
    float ir = gi[t], iz = gi[256+t], inn = gi[512+t];
    float hr = gh[t], hz = gh[256+t], hn = gh[512+t];
    float r = sigf(ir+hr), z = sigf(iz+hz);
    float nn = tanhf(inn + r*hn);
    float hv = (1.0f - z)*nn + z*hold[t];
    hnew[t] = hv;
    h[b*HH + t] = hv;
  }
  __syncthreads();
  if (t < 40){
    const float* Wc; float bias; int col, ld;
    if (t < 16){ Wc=W_op; col=t; ld=16;
      float uu = u[s*BB*16 + b*16 + col];
      bias = b_op[col] + (-logf(-logf(uu + 1e-20f) + 1e-20f)); }
    else if (t<24){ Wc=W_src; col=t-16; ld=8; bias=b_src[col]; }
    else if (t<32){ Wc=W_dst; col=t-24; ld=8; bias=b_dst[col]; }
    else          { Wc=W_aux; col=t-32; ld=8; bias=b_aux[col]; }
    float a = bias;
    for (int k=0;k<HH;++k) a += hnew[k]*Wc[k*ld + col];
    logit[t] = a;
  }
  __syncthreads();
  if (t == 0){
    float m = logit[0]; int am = 0;
    for (int i=1;i<16;++i){ if (logit[i] > m){ m = logit[i]; am = i; } }
    float e[16]; float sum = 0.f;
    for (int i=0;i<16;++i){ e[i] = expf(logit[i]-m); sum += e[i]; }
    float inv = 1.0f/sum;
    for (int i=0;i<16;++i){ float w = e[i]*inv; wsm[i] = w; opw_ws[b*16+i] = w; }
    float hl = halt[b] + wsm[15];
    halt[b] = hl;
    live_ws[b] = fmaxf(1.0f - hl, 0.0f);
    trace_out[b*NSTEPS + s] = (float)am;
  } else if (t <= 3){
    int base = 16 + (t-1)*8;
    float m = logit[base];
    for (int i=1;i<8;++i) m = fmaxf(m, logit[base+i]);
    float e[8]; float sum=0.f;
    for (int i=0;i<8;++i){ e[i]=expf(logit[base+i]-m); sum+=e[i]; }
    float inv = 1.0f/sum;
    for (int i=0;i<8;++i){
      float w = e[i]*inv; wsm[base+i] = w;
      if (t==2) dstw_ws[b*8+i] = w;
    }
  }
  __syncthreads();
  {
    float w4 = wsm[4], w14 = wsm[14], w6 = wsm[6];
    float sx=0,sy=0,sz=0,sw=0, dx=0,dy=0,dz=0,dw_=0, axx=0,ayy=0,azz=0,aww=0;
    #pragma unroll
    for (int r=0;r<8;++r){
      float ws = wsm[16+r], wd = wsm[24+r], wa = wsm[32+r];
      float4 rv = *(const float4*)(regs + (size_t)b*RD + r*DD + t*4);
      sx += ws*rv.x; sy += ws*rv.y; sz += ws*rv.z; sw += ws*rv.w;
      dx += wd*rv.x; dy += wd*rv.y; dz += wd*rv.z; dw_ += wd*rv.w;
      axx += wa*rv.x; ayy += wa*rv.y; azz += wa*rv.z; aww += wa*rv.w;
    }
    float4 o;
    o.x=sx;o.y=sy;o.z=sz;o.w=sw;       *(float4*)(src_ws + b*DD + t*4) = o;
    o.x=dx;o.y=dy;o.z=dz;o.w=dw_;      *(float4*)(dst_ws + b*DD + t*4) = o;
    o.x = w4*sx + w14*sx*dx;  o.y = w4*sy + w14*sy*dy;
    o.z = w4*sz + w14*sz*dz;  o.w = w4*sw + w14*sw*dw_;
    *(float4*)(tvec_ws + b*DD + t*4) = o;
    o.x=w6*axx;o.y=w6*ayy;o.z=w6*azz;o.w=w6*aww;
    *(float4*)(avec_ws + b*DD + t*4) = o;
  }
}

// ---------------- per-step combine + regs update ----------------
__global__ __launch_bounds__(256) void k_combine(
    const float* __restrict__ p8a, const float* __restrict__ p10,
    const float* __restrict__ opw_ws, const float* __restrict__ dstw_ws,
    const float* __restrict__ live_ws,
    const float* __restrict__ src_ws, const float* __restrict__ dst_ws,
    const float* __restrict__ bo, const float* __restrict__ op_scale,
    float* __restrict__ regs)
{
  const int b = blockIdx.x, t = threadIdx.x;
  __shared__ float ow[16], dw[8], redS[4], redQ[4], stats[2];
  if (t<16) ow[t] = opw_ws[b*16+t];
  if (t<8)  dw[t] = dstw_ws[b*8+t];
  float4 sv = *(const float4*)(src_ws + b*DD + t*4);
  float4 dv = *(const float4*)(dst_ws + b*DD + t*4);
  float s1 = sv.x+sv.y+sv.z+sv.w;
  float s2 = sv.x*sv.x + sv.y*sv.y + sv.z*sv.z + sv.w*sv.w;
  #pragma unroll
  for (int off=32; off; off>>=1){ s1 += __shfl_xor(s1, off, 64); s2 += __shfl_xor(s2, off, 64); }
  if ((t&63)==0){ redS[t>>6]=s1; redQ[t>>6]=s2; }
  __syncthreads();
  if (t==0){
    float S = redS[0]+redS[1]+redS[2]+redS[3];
    float Q = redQ[0]+redQ[1]+redQ[2]+redQ[3];
    float mean = S*(1.0f/DD);
    float var = Q*(1.0f/DD) - mean*mean;
    stats[0]=mean; stats[1]=rsqrtf(var + 1e-5f);
  }
  __syncthreads();
  const float mean = stats[0], rstd = stats[1];
  const float live = live_ws[b], osc = op_scale[0];
  float pmx=0,pmy=0,pmz=0,pmw=0, atx=0,aty=0,atz=0,atw=0;
  #pragma unroll
  for (int l=0;l<8;++l){
    float4 v = *(const float4*)(p8a + (size_t)(l*BB+b)*DD + t*4);
    pmx+=v.x; pmy+=v.y; pmz+=v.z; pmw+=v.w;
    float4 w = *(const float4*)(p10 + (size_t)(l*BB+b)*DD + t*4);
    atx+=w.x; aty+=w.y; atz+=w.z; atw+=w.w;
  }
  float4 bo4 = *(const float4*)(bo + t*4);
  atx += ow[6]*bo4.x; aty += ow[6]*bo4.y; atz += ow[6]*bo4.z; atw += ow[6]*bo4.w;
  float S[4]={sv.x,sv.y,sv.z,sv.w}, Dv[4]={dv.x,dv.y,dv.z,dv.w};
  float PM[4]={pmx,pmy,pmz,pmw}, AT[4]={atx,aty,atz,atw};
  float rl[4];
  #pragma unroll
  for (int c=0;c<4;++c){
    float sc=S[c], dc=Dv[c];
    float r = ow[0]*dc + ow[1]*(dc+sc) + ow[2]*(sigf(sc)*dc) + ow[3]*((sc-mean)*rstd)
            + PM[c] + ow[5]*(sc+dc) + AT[c]
            - ow[7]*sc + ow[8]*(sc*osc) + ow[9]*sc
            + ow[10]*fmaxf(sc,dc) + ow[11]*fminf(sc,dc) + ow[12]*fmaxf(sc,0.0f)
            + ow[13]*tanhf(sc) + ow[15]*dc;
    rl[c] = r*live;
  }
  #pragma unroll
  for (int r=0;r<8;++r){
    float4* rp = (float4*)(regs + (size_t)b*RD + r*DD + t*4);
    float4 rv = *rp;
    rv.x += dw[r]*rl[0]; rv.y += dw[r]*rl[1]; rv.z += dw[r]*rl[2]; rv.w += dw[r]*rl[3];
    *rp = rv;
  }
}

// ---------------- decode: d1 -> prog_out (rmsnorm) + regs out ----------------
__global__ __launch_bounds__(256) void k_decode(
    const float* __restrict__ d1part, const float* __restrict__ b_d1,
    const float* __restrict__ W_d2, const float* __restrict__ b_d2,
    const float* __restrict__ norm_w, const float* __restrict__ regs,
    float* __restrict__ pn_ws, float* __restrict__ out)
{
  const int b = blockIdx.x, t = threadIdx.x;
  __shared__ float d1[HH];
  __shared__ float redQ[4], stats[1];
  float a = b_d1[t];
  for (int l=0;l<64;++l) a += d1part[(size_t)(l*BB+b)*HH + t];
  d1[t] = geluf(a);
  __syncthreads();
  float4 acc = *(const float4*)(b_d2 + t*4);
  #pragma unroll 4
  for (int k=0;k<HH;++k){
    float4 w = *(const float4*)(W_d2 + (size_t)k*DD + t*4);
    float dk = d1[k];
    acc.x += dk*w.x; acc.y += dk*w.y; acc.z += dk*w.z; acc.w += dk*w.w;
  }
  float q = acc.x*acc.x + acc.y*acc.y + acc.z*acc.z + acc.w*acc.w;
  #pragma unroll
  for (int off=32; off; off>>=1) q += __shfl_xor(q, off, 64);
  if ((t&63)==0) redQ[t>>6]=q;
  __syncthreads();
  if (t==0) stats[0] = rsqrtf((redQ[0]+redQ[1]+redQ[2]+redQ[3])*(1.0f/DD) + 1e-6f);
  __syncthreads();
  const float rs = stats[0];
  float4 nw = *(const float4*)(norm_w + t*4);
  float4 po;
  po.x = acc.x*rs*nw.x; po.y = acc.y*rs*nw.y; po.z = acc.z*rs*nw.z; po.w = acc.w*rs*nw.w;
  *(float4*)(pn_ws + (size_t)b*DD + t*4) = po;
  *(float4*)(out + OUT_PO + (size_t)b*DD + t*4) = po;
  const float4* rsrc = (const float4*)(regs + (size_t)b*RD);
  float4* rdst = (float4*)(out + OUT_REGS + (size_t)b*RD);
  for (int i=t;i<RD/4;i+=256) rdst[i] = rsrc[i];
}

// ---------------- x_prog = rmsnorm(x + 0.1*pn, norm_w) ----------------
__global__ __launch_bounds__(256) void k_xprog(
    const float* __restrict__ x, const float* __restrict__ pn,
    const float* __restrict__ norm_w, float* __restrict__ out)
{
  const int t = threadIdx.x;
  const int lane = t & 63;
  const int wid = blockIdx.x*4 + (t>>6);   // 0..8191
  const int d0 = lane*16;
  float4 nw0 = *(const float4*)(norm_w + d0);
  float4 nw1 = *(const float4*)(norm_w + d0 + 4);
  float4 nw2 = *(const float4*)(norm_w + d0 + 8);
  float4 nw3 = *(const float4*)(norm_w + d0 + 12);
  for (int r=0;r<8;++r){
    int row = wid + r*8192;
    int b = row >> 11;
    const float* xp = x + (size_t)row*DD + d0;
    const float* pp = pn + (size_t)b*DD + d0;
    float4 y[4]; float ss = 0.f;
    #pragma unroll
    for (int j=0;j<4;++j){
      float4 xv = *(const float4*)(xp + j*4);
      float4 pv = *(const float4*)(pp + j*4);
      y[j].x = xv.x + 0.1f*pv.x; y[j].y = xv.y + 0.1f*pv.y;
      y[j].z = xv.z + 0.1f*pv.z; y[j].w = xv.w + 0.1f*pv.w;
      ss += y[j].x*y[j].x + y[j].y*y[j].y + y[j].z*y[j].z + y[j].w*y[j].w;
    }
    #pragma unroll
    for (int off=32; off; off>>=1) ss += __shfl_xor(ss, off, 64);
    float rsd = rsqrtf(ss*(1.0f/DD) + 1e-6f);
    float* op = out + (size_t)row*DD + d0;
    float4 o;
    o.x=y[0].x*rsd*nw0.x; o.y=y[0].y*rsd*nw0.y; o.z=y[0].z*rsd*nw0.z; o.w=y[0].w*rsd*nw0.w; *(float4*)(op+0)=o;
    o.x=y[1].x*rsd*nw1.x; o.y=y[1].y*rsd*nw1.y; o.z=y[1].z*rsd*nw1.z; o.w=y[1].w*rsd*nw1.w; *(float4*)(op+4)=o;
    o.x=y[2].x*rsd*nw2.x; o.y=y[2].y*rsd*nw2.y; o.z=y[2].z*rsd*nw2.z; o.w=y[2].w*rsd*nw2.w; *(float4*)(op+8)=o;
    o.x=y[3].x*rsd*nw3.x; o.y=y[3].y*rsd*nw3.y; o.z=y[3].z*rsd*nw3.z; o.w=y[3].w*rsd*nw3.w; *(float4*)(op+12)=o;
  }
}

extern "C" void kernel_launch(void* const* d_in, const int* in_sizes, int n_in,
                              void* d_out, int out_size, void* d_ws, size_t ws_size,
                              hipStream_t stream)
{
  (void)in_sizes; (void)n_in; (void)out_size; (void)ws_size;
  const float* x     = (const float*)d_in[0];
  const float* u     = (const float*)d_in[1];
  const float* W_e1  = (const float*)d_in[2];
  const float* b_e1  = (const float*)d_in[3];
  const float* W_e2  = (const float*)d_in[4];
  const float* b_e2  = (const float*)d_in[5];
  const float* W_ih  = (const float*)d_in[6];
  const float* b_ih  = (const float*)d_in[7];
  const float* W_hh  = (const float*)d_in[8];
  const float* b_hh  = (const float*)d_in[9];
  const float* h0    = (const float*)d_in[10];
  const float* W_op  = (const float*)d_in[11];
  const float* b_op  = (const float*)d_in[12];
  const float* W_src = (const float*)d_in[13];
  const float* b_src = (const float*)d_in[14];
  const float* W_dst = (const float*)d_in[15];
  const float* b_dst = (const float*)d_in[16];
  const float* W_aux = (const float*)d_in[17];
  const float* b_aux = (const float*)d_in[18];
  const float* W_proj= (const float*)d_in[19];
  const float* op_sc = (const float*)d_in[20];
  const float* Wv    = (const float*)d_in[21];
  const float* bv    = (const float*)d_in[22];
  const float* Wo    = (const float*)d_in[23];
  const float* bo    = (const float*)d_in[24];
  const float* W_d1  = (const float*)d_in[25];
  const float* b_d1  = (const float*)d_in[26];
  const float* W_d2  = (const float*)d_in[27];
  const float* b_d2  = (const float*)d_in[28];
  const float* norm_w= (const float*)d_in[29];
  float* out = (float*)d_out;
  float* ws  = (float*)d_ws;

  size_t o = 0;
  float* pool_part = ws + o; o += 32UL*32*1024;
  float* pooled    = ws + o; o += 32UL*1024;
  float* e1        = ws + o; o += 32UL*256;
  float* e2part    = ws + o; o += 2UL*32*8192;
  float* regs      = ws + o; o += 32UL*8192;
  float* gip_part  = ws + o; o += 8UL*32*768;
  float* gi_part   = ws + o; o += 64UL*32*768;
  float* hbuf      = ws + o; o += 32UL*256;
  float* halt      = ws + o; o += 32;
  float* opw       = ws + o; o += 32*16;
  float* dstw      = ws + o; o += 32*8;
  float* live      = ws + o; o += 32;
  float* srcv      = ws + o; o += 32UL*1024;
  float* dstv      = ws + o; o += 32UL*1024;
  float* tvec      = ws + o; o += 32UL*1024;
  float* avec      = ws + o; o += 32UL*1024;
  float* p8a       = ws + o; o += 8UL*32*1024;
  float* p8b       = ws + o; o += 8UL*32*1024;
  float* p10       = ws + o; o += 8UL*32*1024;
  float* d1part    = ws + o; o += 64UL*32*256;
  float* pn        = ws + o; o += 32UL*1024;

  hipLaunchKernelGGL(k_pool_part, dim3(1024), dim3(256), 0, stream, x, pool_part);
  hipLaunchKernelGGL(k_pool_fin,  dim3(32),   dim3(256), 0, stream, pool_part, pooled, h0, hbuf, halt);
  hipLaunchKernelGGL(k_e1,        dim3(32),   dim3(256), 0, stream, pooled, W_e1, b_e1, e1);
  hipLaunchKernelGGL(k_mm_part,   dim3(128,2),dim3(128), 0, stream, e1, 256, W_e2, 0, 8192, e2part);
  hipLaunchKernelGGL(k_e2fin,     dim3(1024), dim3(256), 0, stream, e2part, b_e2, regs);
  hipLaunchKernelGGL(k_mm_part,   dim3(12,8), dim3(128), 0, stream, pooled, 1024, W_ih, 0, 768, gip_part);

  for (int s=0;s<NSTEPS;++s){
    hipLaunchKernelGGL(k_mm_part, dim3(12,64), dim3(128), 0, stream, regs, 8192, W_ih, 1024, 768, gi_part);
    hipLaunchKernelGGL(k_control, dim3(32), dim3(256), 0, stream, s, u, gip_part, gi_part,
                       b_ih, W_hh, b_hh, W_op, b_op, W_src, b_src, W_dst, b_dst, W_aux, b_aux,
                       regs, hbuf, halt, opw, dstw, live, srcv, dstv, tvec, avec, out + OUT_TR);
    hipLaunchKernelGGL(k_mm_part, dim3(16,8), dim3(128), 0, stream, tvec, 1024, W_proj, 0, 1024, p8a);
    hipLaunchKernelGGL(k_mm_part, dim3(16,8), dim3(128), 0, stream, avec, 1024, Wv, 0, 1024, p8b);
    hipLaunchKernelGGL(k_mm_attn, dim3(16,8), dim3(128), 0, stream, p8b, opw, bv, Wo, p10);
    hipLaunchKernelGGL(k_combine, dim3(32), dim3(256), 0, stream, p8a, p10, opw, dstw, live,
                       srcv, dstv, bo, op_sc, regs);
  }

  hipLaunchKernelGGL(k_mm_part, dim3(4,64), dim3(128), 0, stream, regs, 8192, W_d1, 0, 256, d1part);
  hipLaunchKernelGGL(k_decode,  dim3(32),  dim3(256), 0, stream, d1part, b_d1, W_d2, b_d2, norm_w, regs, pn, out);
  hipLaunchKernelGGL(k_xprog,   dim3(2048),dim3(256), 0, stream, x, pn, norm_w, out);
}

// Round 2
// 837.816 us; speedup vs baseline: 1.0715x; 1.0715x over previous
//
#include <hip/hip_runtime.h>
#include <math.h>
#include <stddef.h>

#define BB 32
#define LL 2048
#define DD 1024
#define HH 256
#define NSTEPS 4
#define RD 8192
#define G3 768

#define OUT_REGS 67108864UL
#define OUT_PO   67371008UL
#define OUT_TR   67403776UL

__device__ __forceinline__ float sigf(float x){ return 1.0f/(1.0f+expf(-x)); }
__device__ __forceinline__ float geluf(float x){ return x*0.5f*(1.0f+erff(x*0.70710678118654752f)); }

// ---------------- pooled partial: mean_L x ----------------
__global__ __launch_bounds__(256) void k_pool_part(const float* __restrict__ x, float* __restrict__ part){
  const int blk = blockIdx.x;          // b*32 + c
  const int b = blk >> 5, c = blk & 31;
  const int t = threadIdx.x;
  const float* xp = x + (size_t)b*LL*DD + (size_t)c*64*DD + t*4;
  float ax=0.f, ay=0.f, az=0.f, aw=0.f;
  #pragma unroll 4
  for (int l=0;l<64;++l){
    float4 v = *(const float4*)(xp + (size_t)l*DD);
    ax+=v.x; ay+=v.y; az+=v.z; aw+=v.w;
  }
  float4 o; o.x=ax; o.y=ay; o.z=az; o.w=aw;
  *(float4*)(part + (size_t)blk*DD + t*4) = o;
}

// ---------------- fused: pooled finalize + init h/halt + e1 ----------------
__global__ __launch_bounds__(256) void k_pool_e1(const float* __restrict__ part, float* __restrict__ pooled,
                                                 const float* __restrict__ h0, float* __restrict__ h,
                                                 float* __restrict__ halt,
                                                 const float* __restrict__ We1, const float* __restrict__ be1,
                                                 float* __restrict__ e1){
  __shared__ float p[DD];
  const int b = blockIdx.x, t = threadIdx.x;
  float ax=0.f, ay=0.f, az=0.f, aw=0.f;
  #pragma unroll 8
  for (int c=0;c<32;++c){
    float4 v = *(const float4*)(part + (size_t)(b*32+c)*DD + t*4);
    ax+=v.x; ay+=v.y; az+=v.z; aw+=v.w;
  }
  const float inv = 1.0f/(float)LL;
  float4 o; o.x=ax*inv; o.y=ay*inv; o.z=az*inv; o.w=aw*inv;
  *(float4*)(pooled + (size_t)b*DD + t*4) = o;
  *(float4*)(p + t*4) = o;
  h[b*HH + t] = h0[t];
  if (t==0) halt[b] = 0.f;
  __syncthreads();
  float a0=0.f,a1=0.f,a2=0.f,a3=0.f;
  #pragma unroll 2
  for (int k=0;k<DD;k+=4){
    a0 += p[k]  *We1[(k)*HH + t];
    a1 += p[k+1]*We1[(k+1)*HH + t];
    a2 += p[k+2]*We1[(k+2)*HH + t];
    a3 += p[k+3]*We1[(k+3)*HH + t];
  }
  float a = (a0+a1)+(a2+a3) + be1[t];
  e1[b*HH + t] = geluf(a);
}

// ---------------- generic B-shared partial matmul ----------------
#define MM_KC 128
#define ATS 516  // per-bq stride: 128*4 + 4

__device__ __forceinline__ void mm_compute_store(const float* At, const float* Wt,
                                                 float* __restrict__ part, int kc, int n0, int ldw, int t){
  const int nq = t & 15, bq = t >> 4;
  float acc00=0,acc01=0,acc02=0,acc03=0, acc10=0,acc11=0,acc12=0,acc13=0;
  float acc20=0,acc21=0,acc22=0,acc23=0, acc30=0,acc31=0,acc32=0,acc33=0;
  const float4* A4 = (const float4*)At + bq*129;   // 516/4
  const float4* W4 = (const float4*)Wt + nq;
  #pragma unroll 4
  for (int kk=0; kk<MM_KC; ++kk){
    float4 a = A4[kk];
    float4 w = W4[kk*16];
    acc00 += a.x*w.x; acc01 += a.x*w.y; acc02 += a.x*w.z; acc03 += a.x*w.w;
    acc10 += a.y*w.x; acc11 += a.y*w.y; acc12 += a.y*w.z; acc13 += a.y*w.w;
    acc20 += a.z*w.x; acc21 += a.z*w.y; acc22 += a.z*w.z; acc23 += a.z*w.w;
    acc30 += a.w*w.x; acc31 += a.w*w.y; acc32 += a.w*w.z; acc33 += a.w*w.w;
  }
  float* pp = part + (size_t)(kc*32 + bq*4)*ldw + n0 + nq*4;
  float4 o;
  o.x=acc00;o.y=acc01;o.z=acc02;o.w=acc03; *(float4*)(pp + 0*(size_t)ldw) = o;
  o.x=acc10;o.y=acc11;o.z=acc12;o.w=acc13; *(float4*)(pp + 1*(size_t)ldw) = o;
  o.x=acc20;o.y=acc21;o.z=acc22;o.w=acc23; *(float4*)(pp + 2*(size_t)ldw) = o;
  o.x=acc30;o.y=acc31;o.z=acc32;o.w=acc33; *(float4*)(pp + 3*(size_t)ldw) = o;
}

__device__ __forceinline__ void mm_body(const float* __restrict__ in, int in_ld,
                                        const float* __restrict__ W, int row_off, int ldw,
                                        float* __restrict__ part,
                                        float* At, float* Wt, int nb, int kc, int t){
  const int k0 = kc*MM_KC, n0 = nb*64;
  #pragma unroll
  for (int rep=0; rep<8; ++rep){
    int idx = t + rep*128;
    int b = idx & 31, k4 = idx >> 5;
    float4 g = *(const float4*)(in + (size_t)b*in_ld + k0 + k4*4);
    float* a = At + (b>>2)*ATS + k4*16 + (b&3);
    a[0]=g.x; a[4]=g.y; a[8]=g.z; a[12]=g.w;
  }
  #pragma unroll
  for (int rep=0; rep<16; ++rep){
    int idx = t + rep*128;
    int k = idx >> 4, nq4 = idx & 15;
    *(float4*)(Wt + k*64 + nq4*4) = *(const float4*)(W + (size_t)(row_off + k0 + k)*ldw + n0 + nq4*4);
  }
  __syncthreads();
  mm_compute_store(At, Wt, part, kc, n0, ldw, t);
}

__global__ __launch_bounds__(128) void k_mm_part(const float* __restrict__ in, int in_ld,
                                                 const float* __restrict__ W, int row_off, int ldw,
                                                 float* __restrict__ part){
  __shared__ float At[8*ATS];
  __shared__ float Wt[MM_KC*64];
  mm_body(in, in_ld, W, row_off, ldw, part, At, Wt, blockIdx.x, blockIdx.y, threadIdx.x);
}

// fused pair: z=0 -> tvec@W_proj->p8a ; z=1 -> avec@Wv->p8b
__global__ __launch_bounds__(128) void k_mm_z(const float* __restrict__ inA, const float* __restrict__ WA,
                                              float* __restrict__ outA,
                                              const float* __restrict__ inB, const float* __restrict__ WB,
                                              float* __restrict__ outB){
  __shared__ float At[8*ATS];
  __shared__ float Wt[MM_KC*64];
  const float* in = blockIdx.z ? inB : inA;
  const float* W  = blockIdx.z ? WB  : WA;
  float* part     = blockIdx.z ? outB : outA;
  mm_body(in, DD, W, 0, DD, part, At, Wt, blockIdx.x, blockIdx.y, threadIdx.x);
}

// attn second matmul: A assembled as v' = sum_l p8b[l] + opw6*bv, then @ Wo
__global__ __launch_bounds__(128) void k_mm_attn(const float* __restrict__ p8b, const float* __restrict__ opw,
                                                 const float* __restrict__ bv, const float* __restrict__ Wo,
                                                 float* __restrict__ p10){
  __shared__ float At[8*ATS];
  __shared__ float Wt[MM_KC*64];
  const int t = threadIdx.x;
  const int nb = blockIdx.x, kc = blockIdx.y;
  const int k0 = kc*MM_KC, n0 = nb*64;
  #pragma unroll
  for (int rep=0; rep<8; ++rep){
    int idx = t + rep*128;
    int b = idx & 31, k4 = idx >> 5;
    float w6 = opw[b*16 + 6];
    const float* bvp = bv + k0 + k4*4;
    float gx = w6*bvp[0], gy = w6*bvp[1], gz = w6*bvp[2], gw = w6*bvp[3];
    #pragma unroll
    for (int l=0;l<8;++l){
      const float4 pv = *(const float4*)(p8b + (size_t)(l*32+b)*DD + k0 + k4*4);
      gx += pv.x; gy += pv.y; gz += pv.z; gw += pv.w;
    }
    float* a = At + (b>>2)*ATS + k4*16 + (b&3);
    a[0]=gx; a[4]=gy; a[8]=gz; a[12]=gw;
  }
  #pragma unroll
  for (int rep=0; rep<16; ++rep){
    int idx = t + rep*128;
    int k = idx >> 4, nq4 = idx & 15;
    *(float4*)(Wt + k*64 + nq4*4) = *(const float4*)(Wo + (size_t)(k0 + k)*DD + n0 + nq4*4);
  }
  __syncthreads();
  mm_compute_store(At, Wt, p10, kc, n0, DD, t);
}

// regs = e2part(2 layers) + b_e2
__global__ __launch_bounds__(256) void k_e2fin(const float* __restrict__ part, const float* __restrict__ be2,
                                               float* __restrict__ regs){
  int gid = blockIdx.x*256 + threadIdx.x;
  int b = gid >> 13, n = gid & 8191;
  regs[gid] = be2[n] + part[(size_t)(0*32+b)*RD + n] + part[(size_t)(1*32+b)*RD + n];
}

// ---------------- per-step control ----------------
__global__ __launch_bounds__(256) void k_control(int s,
    const float* __restrict__ u,
    const float* __restrict__ gip_part, const float* __restrict__ gi_part,
    const float* __restrict__ b_ih,
    const float* __restrict__ W_hh, const float* __restrict__ b_hh,
    const float* __restrict__ W_op, const float* __restrict__ b_op,
    const float* __restrict__ W_src, const float* __restrict__ b_src,
    const float* __restrict__ W_dst, const float* __restrict__ b_dst,
    const float* __restrict__ W_aux, const float* __restrict__ b_aux,
    const float* __restrict__ regs,
    float* __restrict__ h, float* __restrict__ halt,
    float* __restrict__ opw_ws, float* __restrict__ dstw_ws, float* __restrict__ live_ws,
    float* __restrict__ src_ws, float* __restrict__ dst_ws,
    float* __restrict__ tvec_ws, float* __restrict__ avec_ws,
    float* __restrict__ trace_out)
{
  const int b = blockIdx.x, t = threadIdx.x;
  __shared__ float gi[G3], gh[G3], hold[HH], hnew[HH], logit[40], wsm[40];
  hold[t] = h[b*HH + t];
  #pragma unroll
  for (int j=0;j<3;++j){
    int n = t + j*256;
    float a = b_ih[n];
    #pragma unroll
    for (int l=0;l<8;++l)  a += gip_part[(size_t)(l*BB+b)*G3 + n];
    #pragma unroll 8
    for (int l=0;l<64;++l) a += gi_part[(size_t)(l*BB+b)*G3 + n];
    gi[n] = a;
  }
  __syncthreads();
  #pragma unroll
  for (int j=0;j<3;++j){
    int n = t + j*256;
    float a = b_hh[n];
    #pragma unroll 4
    for (int k=0;k<HH;++k) a += hold[k]*W_hh[k*G3 + n];
    gh[n] = a;
  }
  __syncthreads();
  {
    float ir = gi[t], iz = gi[256+t], inn = gi[512+t];
    float hr = gh[t], hz = gh[256+t], hn = gh[512+t];
    float r = sigf(ir+hr), z = sigf(iz+hz);
    float nn = tanhf(inn + r*hn);
    float hv = (1.0f - z)*nn + z*hold[t];
    hnew[t] = hv;
    h[b*HH + t] = hv;
  }
  __syncthreads();
  if (t < 40){
    const float* Wc; float bias; int col, ld;
    if (t < 16){ Wc=W_op; col=t; ld=16;
      float uu = u[s*BB*16 + b*16 + col];
      bias = b_op[col] + (-logf(-logf(uu + 1e-20f) + 1e-20f)); }
    else if (t<24){ Wc=W_src; col=t-16; ld=8; bias=b_src[col]; }
    else if (t<32){ Wc=W_dst; col=t-24; ld=8; bias=b_dst[col]; }
    else          { Wc=W_aux; col=t-32; ld=8; bias=b_aux[col]; }
    float a = bias;
    #pragma unroll 4
    for (int k=0;k<HH;++k) a += hnew[k]*Wc[k*ld + col];
    logit[t] = a;
  }
  __syncthreads();
  if (t == 0){
    float m = logit[0]; int am = 0;
    for (int i=1;i<16;++i){ if (logit[i] > m){ m = logit[i]; am = i; } }
    float e[16]; float sum = 0.f;
    for (int i=0;i<16;++i){ e[i] = expf(logit[i]-m); sum += e[i]; }
    float inv = 1.0f/sum;
    for (int i=0;i<16;++i){ float w = e[i]*inv; wsm[i] = w; opw_ws[b*16+i] = w; }
    float hl = halt[b] + wsm[15];
    halt[b] = hl;
    live_ws[b] = fmaxf(1.0f - hl, 0.0f);
    trace_out[b*NSTEPS + s] = (float)am;
  } else if (t <= 3){
    int base = 16 + (t-1)*8;
    float m = logit[base];
    for (int i=1;i<8;++i) m = fmaxf(m, logit[base+i]);
    float e[8]; float sum=0.f;
    for (int i=0;i<8;++i){ e[i]=expf(logit[base+i]-m); sum+=e[i]; }
    float inv = 1.0f/sum;
    for (int i=0;i<8;++i){
      float w = e[i]*inv; wsm[base+i] = w;
      if (t==2) dstw_ws[b*8+i] = w;
    }
  }
  __syncthreads();
  {
    float w4 = wsm[4], w14 = wsm[14], w6 = wsm[6];
    float sx=0,sy=0,sz=0,sw=0, dx=0,dy=0,dz=0,dw_=0, axx=0,ayy=0,azz=0,aww=0;
    #pragma unroll
    for (int r=0;r<8;++r){
      float ws = wsm[16+r], wd = wsm[24+r], wa = wsm[32+r];
      float4 rv = *(const float4*)(regs + (size_t)b*RD + r*DD + t*4);
      sx += ws*rv.x; sy += ws*rv.y; sz += ws*rv.z; sw += ws*rv.w;
      dx += wd*rv.x; dy += wd*rv.y; dz += wd*rv.z; dw_ += wd*rv.w;
      axx += wa*rv.x; ayy += wa*rv.y; azz += wa*rv.z; aww += wa*rv.w;
    }
    float4 o;
    o.x=sx;o.y=sy;o.z=sz;o.w=sw;       *(float4*)(src_ws + b*DD + t*4) = o;
    o.x=dx;o.y=dy;o.z=dz;o.w=dw_;      *(float4*)(dst_ws + b*DD + t*4) = o;
    o.x = w4*sx + w14*sx*dx;  o.y = w4*sy + w14*sy*dy;
    o.z = w4*sz + w14*sz*dz;  o.w = w4*sw + w14*sw*dw_;
    *(float4*)(tvec_ws + b*DD + t*4) = o;
    o.x=w6*axx;o.y=w6*ayy;o.z=w6*azz;o.w=w6*aww;
    *(float4*)(avec_ws + b*DD + t*4) = o;
  }
}

// ---------------- per-step combine + regs update ----------------
__global__ __launch_bounds__(256) void k_combine(
    const float* __restrict__ p8a, const float* __restrict__ p10,
    const float* __restrict__ opw_ws, const float* __restrict__ dstw_ws,
    const float* __restrict__ live_ws,
    const float* __restrict__ src_ws, const float* __restrict__ dst_ws,
    const float* __restrict__ bo, const float* __restrict__ op_scale,
    float* __restrict__ regs)
{
  const int b = blockIdx.x, t = threadIdx.x;
  __shared__ float ow[16], dw[8], redS[4], redQ[4], stats[2];
  if (t<16) ow[t] = opw_ws[b*16+t];
  if (t<8)  dw[t] = dstw_ws[b*8+t];
  float4 sv = *(const float4*)(src_ws + b*DD + t*4);
  float4 dv = *(const float4*)(dst_ws + b*DD + t*4);
  float s1 = sv.x+sv.y+sv.z+sv.w;
  float s2 = sv.x*sv.x + sv.y*sv.y + sv.z*sv.z + sv.w*sv.w;
  #pragma unroll
  for (int off=32; off; off>>=1){ s1 += __shfl_xor(s1, off, 64); s2 += __shfl_xor(s2, off, 64); }
  if ((t&63)==0){ redS[t>>6]=s1; redQ[t>>6]=s2; }
  __syncthreads();
  if (t==0){
    float S = redS[0]+redS[1]+redS[2]+redS[3];
    float Q = redQ[0]+redQ[1]+redQ[2]+redQ[3];
    float mean = S*(1.0f/DD);
    float var = Q*(1.0f/DD) - mean*mean;
    stats[0]=mean; stats[1]=rsqrtf(var + 1e-5f);
  }
  __syncthreads();
  const float mean = stats[0], rstd = stats[1];
  const float live = live_ws[b], osc = op_scale[0];
  float pmx=0,pmy=0,pmz=0,pmw=0, atx=0,aty=0,atz=0,atw=0;
  #pragma unroll
  for (int l=0;l<8;++l){
    float4 v = *(const float4*)(p8a + (size_t)(l*BB+b)*DD + t*4);
    pmx+=v.x; pmy+=v.y; pmz+=v.z; pmw+=v.w;
    float4 w = *(const float4*)(p10 + (size_t)(l*BB+b)*DD + t*4);
    atx+=w.x; aty+=w.y; atz+=w.z; atw+=w.w;
  }
  float4 bo4 = *(const float4*)(bo + t*4);
  atx += ow[6]*bo4.x; aty += ow[6]*bo4.y; atz += ow[6]*bo4.z; atw += ow[6]*bo4.w;
  float S[4]={sv.x,sv.y,sv.z,sv.w}, Dv[4]={dv.x,dv.y,dv.z,dv.w};
  float PM[4]={pmx,pmy,pmz,pmw}, AT[4]={atx,aty,atz,atw};
  float rl[4];
  #pragma unroll
  for (int c=0;c<4;++c){
    float sc=S[c], dc=Dv[c];
    float r = ow[0]*dc + ow[1]*(dc+sc) + ow[2]*(sigf(sc)*dc) + ow[3]*((sc-mean)*rstd)
            + PM[c] + ow[5]*(sc+dc) + AT[c]
            - ow[7]*sc + ow[8]*(sc*osc) + ow[9]*sc
            + ow[10]*fmaxf(sc,dc) + ow[11]*fminf(sc,dc) + ow[12]*fmaxf(sc,0.0f)
            + ow[13]*tanhf(sc) + ow[15]*dc;
    rl[c] = r*live;
  }
  #pragma unroll
  for (int r=0;r<8;++r){
    float4* rp = (float4*)(regs + (size_t)b*RD + r*DD + t*4);
    float4 rv = *rp;
    rv.x += dw[r]*rl[0]; rv.y += dw[r]*rl[1]; rv.z += dw[r]*rl[2]; rv.w += dw[r]*rl[3];
    *rp = rv;
  }
}

// ---------------- decode: d1 -> prog_out (rmsnorm) + regs out ----------------
__global__ __launch_bounds__(256) void k_decode(
    const float* __restrict__ d1part, const float* __restrict__ b_d1,
    const float* __restrict__ W_d2, const float* __restrict__ b_d2,
    const float* __restrict__ norm_w, const float* __restrict__ regs,
    float* __restrict__ pn_ws, float* __restrict__ out)
{
  const int b = blockIdx.x, t = threadIdx.x;
  __shared__ float d1[HH];
  __shared__ float redQ[4], stats[1];
  float a = b_d1[t];
  #pragma unroll 8
  for (int l=0;l<64;++l) a += d1part[(size_t)(l*BB+b)*HH + t];
  d1[t] = geluf(a);
  __syncthreads();
  float4 acc = *(const float4*)(b_d2 + t*4);
  #pragma unroll 4
  for (int k=0;k<HH;++k){
    float4 w = *(const float4*)(W_d2 + (size_t)k*DD + t*4);
    float dk = d1[k];
    acc.x += dk*w.x; acc.y += dk*w.y; acc.z += dk*w.z; acc.w += dk*w.w;
  }
  float q = acc.x*acc.x + acc.y*acc.y + acc.z*acc.z + acc.w*acc.w;
  #pragma unroll
  for (int off=32; off; off>>=1) q += __shfl_xor(q, off, 64);
  if ((t&63)==0) redQ[t>>6]=q;
  __syncthreads();
  if (t==0) stats[0] = rsqrtf((redQ[0]+redQ[1]+redQ[2]+redQ[3])*(1.0f/DD) + 1e-6f);
  __syncthreads();
  const float rs = stats[0];
  float4 nw = *(const float4*)(norm_w + t*4);
  float4 po;
  po.x = acc.x*rs*nw.x; po.y = acc.y*rs*nw.y; po.z = acc.z*rs*nw.z; po.w = acc.w*rs*nw.w;
  *(float4*)(pn_ws + (size_t)b*DD + t*4) = po;
  *(float4*)(out + OUT_PO + (size_t)b*DD + t*4) = po;
  const float4* rsrc = (const float4*)(regs + (size_t)b*RD);
  float4* rdst = (float4*)(out + OUT_REGS + (size_t)b*RD);
  for (int i=t;i<RD/4;i+=256) rdst[i] = rsrc[i];
}

// ---------------- x_prog = rmsnorm(x + 0.1*pn, norm_w) ----------------
// one wave per 4 consecutive rows; lane-contiguous float4 accesses.
__global__ __launch_bounds__(256) void k_xprog(
    const float* __restrict__ x, const float* __restrict__ pn,
    const float* __restrict__ norm_w, float* __restrict__ out)
{
  const int t = threadIdx.x;
  const int lane = t & 63;
  const int w = blockIdx.x*4 + (t>>6);   // 0..16383
  const int row0 = w*4;
  const int b = row0 >> 11;              // constant across the wave's 4 rows
  float4 nw[4], pv[4];
  #pragma unroll
  for (int j=0;j<4;++j){
    nw[j] = *(const float4*)(norm_w + j*256 + lane*4);
    float4 p = *(const float4*)(pn + (size_t)b*DD + j*256 + lane*4);
    pv[j].x = 0.1f*p.x; pv[j].y = 0.1f*p.y; pv[j].z = 0.1f*p.z; pv[j].w = 0.1f*p.w;
  }
  #pragma unroll
  for (int r=0;r<4;++r){
    const int row = row0 + r;
    const float* xp = x + (size_t)row*DD;
    float4 y[4]; float ss = 0.f;
    #pragma unroll
    for (int j=0;j<4;++j){
      float4 xv = *(const float4*)(xp + j*256 + lane*4);
      y[j].x = xv.x + pv[j].x; y[j].y = xv.y + pv[j].y;
      y[j].z = xv.z + pv[j].z; y[j].w = xv.w + pv[j].w;
      ss += y[j].x*y[j].x + y[j].y*y[j].y + y[j].z*y[j].z + y[j].w*y[j].w;
    }
    #pragma unroll
    for (int off=32; off; off>>=1) ss += __shfl_xor(ss, off, 64);
    float rsd = rsqrtf(ss*(1.0f/DD) + 1e-6f);
    float* op = out + (size_t)row*DD;
    #pragma unroll
    for (int j=0;j<4;++j){
      float4 o;
      o.x=y[j].x*rsd*nw[j].x; o.y=y[j].y*rsd*nw[j].y;
      o.z=y[j].z*rsd*nw[j].z; o.w=y[j].w*rsd*nw[j].w;
      *(float4*)(op + j*256 + lane*4) = o;
    }
  }
}

extern "C" void kernel_launch(void* const* d_in, const int* in_sizes, int n_in,
                              void* d_out, int out_size, void* d_ws, size_t ws_size,
                              hipStream_t stream)
{
  (void)in_sizes; (void)n_in; (void)out_size; (void)ws_size;
  const float* x     = (const float*)d_in[0];
  const float* u     = (const float*)d_in[1];
  const float* W_e1  = (const float*)d_in[2];
  const float* b_e1  = (const float*)d_in[3];
  const float* W_e2  = (const float*)d_in[4];
  const float* b_e2  = (const float*)d_in[5];
  const float* W_ih  = (const float*)d_in[6];
  const float* b_ih  = (const float*)d_in[7];
  const float* W_hh  = (const float*)d_in[8];
  const float* b_hh  = (const float*)d_in[9];
  const float* h0    = (const float*)d_in[10];
  const float* W_op  = (const float*)d_in[11];
  const float* b_op  = (const float*)d_in[12];
  const float* W_src = (const float*)d_in[13];
  const float* b_src = (const float*)d_in[14];
  const float* W_dst = (const float*)d_in[15];
  const float* b_dst = (const float*)d_in[16];
  const float* W_aux = (const float*)d_in[17];
  const float* b_aux = (const float*)d_in[18];
  const float* W_proj= (const float*)d_in[19];
  const float* op_sc = (const float*)d_in[20];
  const float* Wv    = (const float*)d_in[21];
  const float* bv    = (const float*)d_in[22];
  const float* Wo    = (const float*)d_in[23];
  const float* bo    = (const float*)d_in[24];
  const float* W_d1  = (const float*)d_in[25];
  const float* b_d1  = (const float*)d_in[26];
  const float* W_d2  = (const float*)d_in[27];
  const float* b_d2  = (const float*)d_in[28];
  const float* norm_w= (const float*)d_in[29];
  float* out = (float*)d_out;
  float* ws  = (float*)d_ws;

  size_t o = 0;
  float* pool_part = ws + o; o += 32UL*32*1024;
  float* pooled    = ws + o; o += 32UL*1024;
  float* e1        = ws + o; o += 32UL*256;
  float* e2part    = ws + o; o += 2UL*32*8192;
  float* regs      = ws + o; o += 32UL*8192;
  float* gip_part  = ws + o; o += 8UL*32*768;
  float* gi_part   = ws + o; o += 64UL*32*768;
  float* hbuf      = ws + o; o += 32UL*256;
  float* halt      = ws + o; o += 32;
  float* opw       = ws + o; o += 32*16;
  float* dstw      = ws + o; o += 32*8;
  float* live      = ws + o; o += 32;
  float* srcv      = ws + o; o += 32UL*1024;
  float* dstv      = ws + o; o += 32UL*1024;
  float* tvec      = ws + o; o += 32UL*1024;
  float* avec      = ws + o; o += 32UL*1024;
  float* p8a       = ws + o; o += 8UL*32*1024;
  float* p8b       = ws + o; o += 8UL*32*1024;
  float* p10       = ws + o; o += 8UL*32*1024;
  float* d1part    = ws + o; o += 64UL*32*256;
  float* pn        = ws + o; o += 32UL*1024;

  hipLaunchKernelGGL(k_pool_part, dim3(1024), dim3(256), 0, stream, x, pool_part);
  hipLaunchKernelGGL(k_pool_e1,   dim3(32),   dim3(256), 0, stream, pool_part, pooled, h0, hbuf, halt,
                     W_e1, b_e1, e1);
  hipLaunchKernelGGL(k_mm_part,   dim3(128,2),dim3(128), 0, stream, e1, 256, W_e2, 0, 8192, e2part);
  hipLaunchKernelGGL(k_e2fin,     dim3(1024), dim3(256), 0, stream, e2part, b_e2, regs);
  hipLaunchKernelGGL(k_mm_part,   dim3(12,8), dim3(128), 0, stream, pooled, 1024, W_ih, 0, 768, gip_part);

  for (int s=0;s<NSTEPS;++s){
    hipLaunchKernelGGL(k_mm_part, dim3(12,64), dim3(128), 0, stream, regs, 8192, W_ih, 1024, 768, gi_part);
    hipLaunchKernelGGL(k_control, dim3(32), dim3(256), 0, stream, s, u, gip_part, gi_part,
                       b_ih, W_hh, b_hh, W_op, b_op, W_src, b_src, W_dst, b_dst, W_aux, b_aux,
                       regs, hbuf, halt, opw, dstw, live, srcv, dstv, tvec, avec, out + OUT_TR);
    hipLaunchKernelGGL(k_mm_z,    dim3(16,8,2), dim3(128), 0, stream, tvec, W_proj, p8a, avec, Wv, p8b);
    hipLaunchKernelGGL(k_mm_attn, dim3(16,8), dim3(128), 0, stream, p8b, opw, bv, Wo, p10);
    hipLaunchKernelGGL(k_combine, dim3(32), dim3(256), 0, stream, p8a, p10, opw, dstw, live,
                       srcv, dstv, bo, op_sc, regs);
  }

  hipLaunchKernelGGL(k_mm_part, dim3(4,64), dim3(128), 0, stream, regs, 8192, W_d1, 0, 256, d1part);
  hipLaunchKernelGGL(k_decode,  dim3(32),  dim3(256), 0, stream, d1part, b_d1, W_d2, b_d2, norm_w, regs, pn, out);
  hipLaunchKernelGGL(k_xprog,   dim3(4096),dim3(256), 0, stream, x, pn, norm_w, out);
}